// Round 7
// baseline (94.707 us; speedup 1.0000x reference)
//
#include <hip/hip_runtime.h>
#include <hip/hip_bf16.h>
#include <math.h>

#define N 8192
#define D 128
#define MARGIN_V 0.3f
#define NEG_FILL 1000000.0f

typedef short bf16x8 __attribute__((ext_vector_type(8)));
typedef float f32x4  __attribute__((ext_vector_type(4)));

__device__ __forceinline__ void g2l16(const void* g, void* l) {
    __builtin_amdgcn_global_load_lds(
        (const __attribute__((address_space(1))) void*)g,
        (__attribute__((address_space(3))) void*)l, 16, 0, 0);
}

// ---------- convert: F fp32 -> bf16, sq[i] = ||f_i||^2; init ap/an ----------
__global__ __launch_bounds__(256) void convert_kernel(const float* __restrict__ F,
                                                      unsigned short* __restrict__ Fb,
                                                      float* __restrict__ sq,
                                                      unsigned* __restrict__ ap,
                                                      unsigned* __restrict__ an) {
    int row  = blockIdx.x * 4 + (threadIdx.x >> 6);
    int lane = threadIdx.x & 63;
    float2 v = *(const float2*)&F[row * D + lane * 2];
    float s = v.x * v.x + v.y * v.y;
    __hip_bfloat162 t = __float22bfloat162_rn(v);
    *(unsigned int*)&Fb[row * D + lane * 2] = *(unsigned int*)&t;
    #pragma unroll
    for (int off = 32; off >= 1; off >>= 1) s += __shfl_xor(s, off);
    if (lane == 0) sq[row] = s;
    int gid = blockIdx.x * 256 + threadIdx.x;
    if (gid < N) { ap[gid] = 0u; an[gid] = 0x7F800000u; }   // 0.0f / +inf (d^2 domain)
}

// ---------- gemm: 128-row strip x 1024-col chunk, barrier-free K-loop ----------
// grid 512 = 64 strips x 8 chunks. A tile LDS-staged once, frags cached in regs.
// B fragments loaded global->register directly (L2-resident), double-buffered
// one tile ahead; NO __syncthreads inside the j-tile loop. Mining in
// u = sqj - 2c domain, register-accumulated; sqrt deferred to loss kernel.
__global__ __launch_bounds__(256, 2) void gemm_kernel(const unsigned short* __restrict__ Fb,
                                                      const float* __restrict__ sq,
                                                      const int* __restrict__ lab,
                                                      unsigned* __restrict__ ap,
                                                      unsigned* __restrict__ an) {
    __shared__ __align__(16) unsigned short As[128 * 128];   // 32 KB
    __shared__ float sqj_s[1024];
    __shared__ int   labj_s[1024];
    __shared__ float sqi_s[128];
    __shared__ int   labi_s[128];

    const int bi = blockIdx.x & 63;
    const int jc = blockIdx.x >> 6;
    const int i0 = bi * 128;
    const int jbase0 = jc * 1024;
    const int tid  = threadIdx.x;
    const int wave = tid >> 6, lane = tid & 63;
    const int wy = wave >> 1, wx = wave & 1;   // wave = 64 rows (wy) x 32 cols (wx)
    const int quad = lane >> 4, lr = lane & 15;

    // stage per-row/col metadata
    {
        f32x4 v = *(const f32x4*)&sq[jbase0 + tid * 4];
        *(f32x4*)&sqj_s[tid * 4] = v;
        int4 w4 = *(const int4*)&lab[jbase0 + tid * 4];
        *(int4*)&labj_s[tid * 4] = w4;
    }
    if (tid < 128) { sqi_s[tid] = sq[i0 + tid]; labi_s[tid] = lab[i0 + tid]; }

    // stage A tile (128 rows x 128 k) to LDS, XOR-swizzled chunks
    #pragma unroll
    for (int it = 0; it < 8; ++it) {
        int c_id = it * 256 + tid;
        int row = c_id >> 4, p = c_id & 15;
        int sc = (p & 8) | ((p ^ row) & 7);
        g2l16(Fb + (size_t)(i0 + row) * D + sc * 8, (char*)As + c_id * 16);
    }
    __syncthreads();   // the ONLY barrier

    // cache A fragments in registers: 4 row-frags x 4 k-blocks
    bf16x8 af[4][4];
    #pragma unroll
    for (int a = 0; a < 4; ++a)
        #pragma unroll
        for (int ks = 0; ks < 4; ++ks) {
            int row = wy * 64 + a * 16 + lr;
            int kc  = ks * 4 + quad;
            int pos = (kc & 8) | ((kc ^ row) & 7);
            af[a][ks] = *(const bf16x8*)&As[row * 128 + pos * 8];
        }
    f32x4 sqi4[4]; int4 labi4[4];
    #pragma unroll
    for (int a = 0; a < 4; ++a) {
        int base = wy * 64 + a * 16 + quad * 4;
        sqi4[a]  = *(const f32x4*)&sqi_s[base];
        labi4[a] = *(const int4*)&labi_s[base];
    }

    float rowP[4][4], rowN[4][4];
    #pragma unroll
    for (int a = 0; a < 4; ++a)
        #pragma unroll
        for (int r = 0; r < 4; ++r) { rowP[a][r] = -INFINITY; rowN[a][r] = INFINITY; }

    // B fragment base for this lane: col = jbase0 + t*64 + wx*32 + b*16 + lr
    const unsigned short* Bp = Fb + (size_t)(jbase0 + wx * 32 + lr) * D + quad * 8;
    const int c0 = wx * 32 + lr;

#define LOAD_BTILE(T, DST)                                                      \
    {                                                                           \
        _Pragma("unroll")                                                       \
        for (int b = 0; b < 2; ++b) {                                           \
            const unsigned short* p_ = Bp + (size_t)((T) * 64 + b * 16) * D;    \
            _Pragma("unroll")                                                   \
            for (int ks = 0; ks < 4; ++ks)                                      \
                DST[b][ks] = *(const bf16x8*)(p_ + ks * 32);                    \
        }                                                                       \
    }

#define COMPUTE_TILE(T, BFR)                                                    \
    {                                                                           \
        float sqj_l[2]; int labj_l[2];                                          \
        _Pragma("unroll")                                                       \
        for (int b = 0; b < 2; ++b) {                                           \
            int cl = (T) * 64 + c0 + b * 16;                                    \
            sqj_l[b]  = sqj_s[cl];                                              \
            labj_l[b] = labj_s[cl];                                             \
        }                                                                       \
        f32x4 acc[4][2];                                                        \
        _Pragma("unroll")                                                       \
        for (int a = 0; a < 4; ++a)                                             \
            _Pragma("unroll")                                                   \
            for (int b = 0; b < 2; ++b) acc[a][b] = {0.f, 0.f, 0.f, 0.f};       \
        _Pragma("unroll")                                                       \
        for (int ks = 0; ks < 4; ++ks)                                          \
            _Pragma("unroll")                                                   \
            for (int a = 0; a < 4; ++a)                                         \
                _Pragma("unroll")                                               \
                for (int b = 0; b < 2; ++b)                                     \
                    acc[a][b] = __builtin_amdgcn_mfma_f32_16x16x32_bf16(        \
                        af[a][ks], BFR[b][ks], acc[a][b], 0, 0, 0);             \
        _Pragma("unroll")                                                       \
        for (int a = 0; a < 4; ++a)                                             \
            _Pragma("unroll")                                                   \
            for (int b = 0; b < 2; ++b)                                         \
                _Pragma("unroll")                                               \
                for (int r = 0; r < 4; ++r) {                                   \
                    float u = fmaf(acc[a][b][r], -2.0f, sqj_l[b]);              \
                    bool same = (labi4[a][r] == labj_l[b]);                     \
                    rowP[a][r] = fmaxf(rowP[a][r], same ? u : -INFINITY);       \
                    rowN[a][r] = fminf(rowN[a][r], same ? INFINITY : u);        \
                }                                                               \
    }

    bf16x8 bf0[2][4], bf1[2][4];
    LOAD_BTILE(0, bf0);
    #pragma unroll 1
    for (int t = 0; t < 16; t += 2) {
        LOAD_BTILE(t + 1, bf1);
        COMPUTE_TILE(t, bf0);
        if (t + 2 < 16) LOAD_BTILE(t + 2, bf0);
        COMPUTE_TILE(t + 1, bf1);
    }
#undef LOAD_BTILE
#undef COMPUTE_TILE

    // reduce over the 16 lr lanes, then atomically combine (d^2 bit domain)
    #pragma unroll
    for (int a = 0; a < 4; ++a)
        #pragma unroll
        for (int r = 0; r < 4; ++r) {
            float p = rowP[a][r], n = rowN[a][r];
            #pragma unroll
            for (int off = 1; off < 16; off <<= 1) {
                p = fmaxf(p, __shfl_xor(p, off));
                n = fminf(n, __shfl_xor(n, off));
            }
            rowP[a][r] = p; rowN[a][r] = n;
        }
    if (lr == 0) {
        #pragma unroll
        for (int a = 0; a < 4; ++a)
            #pragma unroll
            for (int r = 0; r < 4; ++r) {
                int row = i0 + wy * 64 + a * 16 + quad * 4 + r;
                float pd2 = fmaxf(sqi4[a][r] + rowP[a][r], 0.f);   // -inf -> 0 (empty pos)
                float nd2 = fmaxf(sqi4[a][r] + rowN[a][r], 0.f);   // +inf stays +inf
                atomicMax(&ap[row], __float_as_uint(pd2));
                atomicMin(&an[row], __float_as_uint(nd2));
            }
    }
}

// ---------- loss: single block, reads d^2, sqrt here, writes out[0] ----------
__global__ __launch_bounds__(256) void loss_kernel(const float* __restrict__ ap,
                                                   const float* __restrict__ an,
                                                   float* __restrict__ out) {
    int tid = threadIdx.x;
    float sum = 0.f;
    #pragma unroll
    for (int k = 0; k < 8; ++k) {
        int i = k * 1024 + tid * 4;
        f32x4 a4 = *(const f32x4*)&ap[i];
        f32x4 n4 = *(const f32x4*)&an[i];
        #pragma unroll
        for (int c = 0; c < 4; ++c) {
            float apd = __builtin_amdgcn_sqrtf(a4[c]);
            float anv = n4[c];
            float and_ = (anv < INFINITY) ? __builtin_amdgcn_sqrtf(anv) : NEG_FILL;
            sum += fmaxf(0.f, MARGIN_V - (and_ - apd));
        }
    }
    #pragma unroll
    for (int off = 32; off >= 1; off >>= 1) sum += __shfl_xor(sum, off);
    __shared__ float s4[4];
    if ((tid & 63) == 0) s4[tid >> 6] = sum;
    __syncthreads();
    if (tid == 0) out[0] = (s4[0] + s4[1] + s4[2] + s4[3]) * (1.0f / (float)N);
}

extern "C" void kernel_launch(void* const* d_in, const int* in_sizes, int n_in,
                              void* d_out, int out_size, void* d_ws, size_t ws_size,
                              hipStream_t stream) {
    const float* F   = (const float*)d_in[0];
    const int*   lab = (const int*)d_in[1];

    unsigned short* Fb = (unsigned short*)d_ws;          // 2 MB
    float*          sq = (float*)(Fb + (size_t)N * D);   // 32 KB
    unsigned*       ap = (unsigned*)(sq + N);            // 32 KB
    unsigned*       an = ap + N;                         // 32 KB

    convert_kernel<<<N / 4, 256, 0, stream>>>(F, Fb, sq, ap, an);
    gemm_kernel<<<512, 256, 0, stream>>>(Fb, sq, lab, ap, an);
    loss_kernel<<<1, 256, 0, stream>>>((const float*)ap, (const float*)an, (float*)d_out);
}